// Round 2
// baseline (114.620 us; speedup 1.0000x reference)
//
#include <hip/hip_runtime.h>
#include <math.h>

// Problem constants (fixed by the reference setup_inputs)
#define B_   8
#define T_   16
#define HW_  262144                 // 512*512
#define N_   (B_*T_*HW_)            // 33,554,432
#define CHUNKS_PER_FRAME 16
#define NBLOCKS (B_*T_*CHUNKS_PER_FRAME)   // 2048
#define CHUNK_ELEMS (HW_/CHUNKS_PER_FRAME) // 16384
#define THREADS 256

#define BOUND_  100.0f
#define ALPHA_  0.1f
#define SMOOTH_ 1e-5f

__device__ __forceinline__ float wave_reduce(float v) {
    #pragma unroll
    for (int off = 32; off >= 1; off >>= 1)
        v += __shfl_down(v, off, 64);
    return v;
}

struct Acc { float bce, pt, p, t, x; };

__device__ __forceinline__ void accum4(const float4 xv, const float4 tv, Acc& a) {
    float xs[4] = {xv.x, xv.y, xv.z, xv.w};
    float ts[4] = {tv.x, tv.y, tv.z, tv.w};
    #pragma unroll
    for (int j = 0; j < 4; ++j) {
        float xx = xs[j], tt = ts[j];
        float ax = fabsf(xx);
        float e  = __expf(-ax);                    // shared by bce + sigmoid
        // bce: max(x,0) - x*t + log1p(exp(-|x|)); e in (0,1] so log(1+e) is safe
        a.bce += fmaxf(xx, 0.f) - xx * tt + __logf(1.f + e);
        float inv = __fdividef(1.f, 1.f + e);
        float sig = (xx >= 0.f) ? inv : e * inv;   // sigmoid via same e
        a.pt += sig * tt;
        a.p  += sig;
        a.t  += tt;
        a.x  += xx;
    }
}

// Fused: streaming partials + last-block finalize.
// Block bid handles elements [bid*16384, (bid+1)*16384) — a contiguous slice
// of one (b,t) frame. Partials layout in ws: [5][NBLOCKS] (bce, pt, p, t, x).
__global__ void __launch_bounds__(THREADS)
fused_kernel(const float* __restrict__ x, const float* __restrict__ tg,
             float* __restrict__ ws, int* __restrict__ counter,
             float* __restrict__ out) {
    const int bid = blockIdx.x;
    const int tid = threadIdx.x;
    const size_t base = (size_t)bid * CHUNK_ELEMS;
    const float4* __restrict__ x4 = (const float4*)(x + base);
    const float4* __restrict__ t4 = (const float4*)(tg + base);

    Acc a = {0.f, 0.f, 0.f, 0.f, 0.f};
    const int n4 = CHUNK_ELEMS / 4;          // 4096; exactly 8 iters of stride 512
    for (int i = tid; i < n4; i += 2 * THREADS) {
        float4 xa = x4[i];
        float4 ta = t4[i];
        float4 xb = x4[i + THREADS];
        float4 tb = t4[i + THREADS];
        accum4(xa, ta, a);
        accum4(xb, tb, a);
    }

    // block reduce (4 waves)
    __shared__ float red[4][5];
    __shared__ int lastf;
    {
        float v[5] = {a.bce, a.pt, a.p, a.t, a.x};
        const int lane = tid & 63, wv = tid >> 6;
        #pragma unroll
        for (int q = 0; q < 5; ++q) {
            float r = wave_reduce(v[q]);
            if (lane == 0) red[wv][q] = r;
        }
    }
    __syncthreads();
    if (tid == 0) {
        #pragma unroll
        for (int q = 0; q < 5; ++q)
            ws[q * NBLOCKS + bid] = red[0][q] + red[1][q] + red[2][q] + red[3][q];
        __threadfence();                        // release partials (device scope)
        int prev = atomicAdd(counter, 1);       // device-scope by default
        lastf = (prev == NBLOCKS - 1) ? 1 : 0;
    }
    __syncthreads();
    if (!lastf) return;

    // ---------------- last block: finalize ----------------
    __threadfence();   // acquire: invalidate L1/L2 before reading others' partials

    __shared__ float frame_s[B_ * T_];   // 128 per-frame x sums
    __shared__ float batch_q[3][B_];     // pt, p, t per batch
    __shared__ float sred[4];
    __shared__ float ssl_val;

    const int lane = tid & 63, wv = tid >> 6;
    const float* wx  = ws + 4 * NBLOCKS;  // x partials

    // frame sums: 128 frames x 16 chunks
    if (tid < B_ * T_) {
        float s = 0.f;
        #pragma unroll
        for (int j = 0; j < CHUNKS_PER_FRAME; ++j)
            s += wx[tid * CHUNKS_PER_FRAME + j];
        frame_s[tid] = s;
    }
    __syncthreads();

    // ssl over the 120 frame diffs (threads 0..119), block reduce
    {
        float sslp = 0.f;
        if (tid < B_ * (T_ - 1)) {
            int b = tid / (T_ - 1), k = tid % (T_ - 1);
            int f = b * T_ + k;
            float d = fabsf(frame_s[f + 1] - frame_s[f]);
            float r = fmaxf(d - BOUND_, 0.f);
            sslp = r * r;
        }
        float r = wave_reduce(sslp);
        if (lane == 0) sred[wv] = r;
    }
    __syncthreads();
    if (tid == 0) ssl_val = sred[0] + sred[1] + sred[2] + sred[3];

    // per-batch sums for pt/p/t: 24 segments (q,b) x 256 values, 8 threads each
    if (tid < 192) {
        int seg = tid >> 3;          // 0..23
        int q = seg >> 3;            // 0..2  -> ws segments 1..3
        int b = seg & 7;             // 0..7
        const float* wq = ws + (q + 1) * NBLOCKS + b * (NBLOCKS / B_);
        float s = 0.f;
        #pragma unroll
        for (int k = 0; k < 32; ++k)
            s += wq[(tid & 7) * 32 + k];
        s += __shfl_down(s, 4, 64);
        s += __shfl_down(s, 2, 64);
        s += __shfl_down(s, 1, 64);
        if ((tid & 7) == 0) batch_q[q][b] = s;
    }
    __syncthreads();   // covers tid0's sred read above AND batch_q writes

    // global bce sum: 2048 partials, 8 per thread
    {
        float s = 0.f;
        #pragma unroll
        for (int k = 0; k < 8; ++k)
            s += ws[tid * 8 + k];
        float r = wave_reduce(s);
        if (lane == 0) sred[wv] = r;
    }
    __syncthreads();

    if (tid == 0) {
        float bce = (sred[0] + sred[1] + sred[2] + sred[3]) / (float)N_;
        float dice_sum = 0.f;
        #pragma unroll
        for (int b = 0; b < B_; ++b) {
            float inter = batch_q[0][b];
            dice_sum += (2.f * inter + SMOOTH_) /
                        (batch_q[1][b] + batch_q[2][b] + SMOOTH_);
        }
        float dice = 1.f - dice_sum / (float)B_;
        out[0] = 0.5f * bce + dice + ALPHA_ * ssl_val;
    }
}

extern "C" void kernel_launch(void* const* d_in, const int* in_sizes, int n_in,
                              void* d_out, int out_size, void* d_ws, size_t ws_size,
                              hipStream_t stream) {
    const float* x  = (const float*)d_in[0];
    const float* tg = (const float*)d_in[1];
    float* ws = (float*)d_ws;                          // 5*2048*4 = 40960 B partials
    int* counter = (int*)((char*)d_ws + 5 * NBLOCKS * sizeof(float));
    float* out = (float*)d_out;

    // counter must be 0 at the start of every call (ws is poisoned once, not
    // re-initialized between replays)
    hipMemsetAsync(counter, 0, sizeof(int), stream);
    fused_kernel<<<NBLOCKS, THREADS, 0, stream>>>(x, tg, ws, counter, out);
}

// Round 3
// 89.313 us; speedup vs baseline: 1.2834x; 1.2834x over previous
//
#include <hip/hip_runtime.h>
#include <math.h>

// Problem constants (fixed by the reference setup_inputs)
#define B_   8
#define T_   16
#define HW_  262144                 // 512*512
#define N_   (B_*T_*HW_)            // 33,554,432
#define CHUNKS_PER_FRAME 16
#define NBLOCKS (B_*T_*CHUNKS_PER_FRAME)   // 2048
#define CHUNK_ELEMS (HW_/CHUNKS_PER_FRAME) // 16384
#define THREADS 256

#define BOUND_  100.0f
#define ALPHA_  0.1f
#define SMOOTH_ 1e-5f

// ws accumulator layout (zeroed each call):
//   [0..127]   per-frame sum(x)
//   [128..135] per-batch sum(p*t)
//   [136..143] per-batch sum(p)
//   [144..151] per-batch sum(t)
//   [152]      global bce sum
#define ACC_FRAME 0
#define ACC_PT    128
#define ACC_P     136
#define ACC_T     144
#define ACC_BCE   152
#define ACC_N     153

__device__ __forceinline__ float wave_reduce(float v) {
    #pragma unroll
    for (int off = 32; off >= 1; off >>= 1)
        v += __shfl_down(v, off, 64);
    return v;
}

// Pass 1: streaming partials, one contiguous 16K-element chunk per block
// (each chunk lies within a single (b,t) frame). Per-block reduce, then
// 5 atomicAdds into the small accumulator array (device-scope by default).
__global__ void __launch_bounds__(THREADS)
partials_kernel(const float* __restrict__ x, const float* __restrict__ tg,
                float* __restrict__ acc) {
    const int bid = blockIdx.x;
    const int tid = threadIdx.x;
    const size_t base = (size_t)bid * CHUNK_ELEMS;
    const float4* __restrict__ x4 = (const float4*)(x + base);
    const float4* __restrict__ t4 = (const float4*)(tg + base);

    float s_bce = 0.f, s_pt = 0.f, s_p = 0.f, s_t = 0.f, s_x = 0.f;

    const int n4 = CHUNK_ELEMS / 4;  // 4096 float4 per block, 16 iters/thread
    for (int i = tid; i < n4; i += THREADS) {
        float4 xv = x4[i];
        float4 tv = t4[i];
        float xs[4] = {xv.x, xv.y, xv.z, xv.w};
        float ts[4] = {tv.x, tv.y, tv.z, tv.w};
        #pragma unroll
        for (int j = 0; j < 4; ++j) {
            float xx = xs[j], tt = ts[j];
            float ax = fabsf(xx);
            float e  = __expf(-ax);                    // shared by bce + sigmoid
            // bce: max(x,0) - x*t + log1p(exp(-|x|)); e in (0,1] so log is safe
            s_bce += fmaxf(xx, 0.f) - xx * tt + __logf(1.f + e);
            float inv = __fdividef(1.f, 1.f + e);
            float sig = (xx >= 0.f) ? inv : e * inv;   // sigmoid via same e
            s_pt += sig * tt;
            s_p  += sig;
            s_t  += tt;
            s_x  += xx;
        }
    }

    // block reduce (4 waves)
    __shared__ float red[4][5];
    float v[5] = {s_bce, s_pt, s_p, s_t, s_x};
    const int lane = tid & 63, wv = tid >> 6;
    #pragma unroll
    for (int q = 0; q < 5; ++q) {
        float r = wave_reduce(v[q]);
        if (lane == 0) red[wv][q] = r;
    }
    __syncthreads();
    if (tid == 0) {
        const int frame = bid >> 4;   // 16 chunks per frame
        const int batch = bid >> 8;   // 256 chunks per batch
        float sb = red[0][0] + red[1][0] + red[2][0] + red[3][0];
        float sp = red[0][1] + red[1][1] + red[2][1] + red[3][1];
        float sg = red[0][2] + red[1][2] + red[2][2] + red[3][2];
        float st = red[0][3] + red[1][3] + red[2][3] + red[3][3];
        float sx = red[0][4] + red[1][4] + red[2][4] + red[3][4];
        atomicAdd(&acc[ACC_BCE], sb);
        atomicAdd(&acc[ACC_PT + batch], sp);
        atomicAdd(&acc[ACC_P  + batch], sg);
        atomicAdd(&acc[ACC_T  + batch], st);
        atomicAdd(&acc[ACC_FRAME + frame], sx);
    }
}

// Pass 2: tiny finalize — 1 block, 128 threads, reads 153 floats.
// Kernel boundary provides cross-XCD visibility of the atomics.
__global__ void __launch_bounds__(128)
finalize_kernel(const float* __restrict__ acc, float* __restrict__ out) {
    __shared__ float sred[2];
    const int tid = threadIdx.x;
    const int lane = tid & 63, wv = tid >> 6;

    // ssl over the 120 frame diffs
    float sslp = 0.f;
    if (tid < B_ * (T_ - 1)) {
        int b = tid / (T_ - 1), k = tid % (T_ - 1);
        int f = b * T_ + k;
        float d = fabsf(acc[ACC_FRAME + f + 1] - acc[ACC_FRAME + f]);
        float r = fmaxf(d - BOUND_, 0.f);
        sslp = r * r;
    }
    float r = wave_reduce(sslp);
    if (lane == 0) sred[wv] = r;
    __syncthreads();

    if (tid == 0) {
        float ssl = sred[0] + sred[1];
        float bce = acc[ACC_BCE] / (float)N_;
        float dice_sum = 0.f;
        #pragma unroll
        for (int b = 0; b < B_; ++b) {
            float inter = acc[ACC_PT + b];
            dice_sum += (2.f * inter + SMOOTH_) /
                        (acc[ACC_P + b] + acc[ACC_T + b] + SMOOTH_);
        }
        float dice = 1.f - dice_sum / (float)B_;
        out[0] = 0.5f * bce + dice + ALPHA_ * ssl;
    }
}

extern "C" void kernel_launch(void* const* d_in, const int* in_sizes, int n_in,
                              void* d_out, int out_size, void* d_ws, size_t ws_size,
                              hipStream_t stream) {
    const float* x  = (const float*)d_in[0];
    const float* tg = (const float*)d_in[1];
    float* acc = (float*)d_ws;     // 153 floats, zeroed every call
    float* out = (float*)d_out;

    hipMemsetAsync(acc, 0, ACC_N * sizeof(float), stream);
    partials_kernel<<<NBLOCKS, THREADS, 0, stream>>>(x, tg, acc);
    finalize_kernel<<<1, 128, 0, stream>>>(acc, out);
}

// Round 4
// 52.289 us; speedup vs baseline: 2.1921x; 1.7081x over previous
//
#include <hip/hip_runtime.h>
#include <math.h>

// Problem constants (fixed by the reference setup_inputs)
#define B_   8
#define T_   16
#define HW_  262144                 // 512*512
#define N_   (B_*T_*HW_)            // 33,554,432
#define CHUNKS_PER_FRAME 16
#define NBLOCKS (B_*T_*CHUNKS_PER_FRAME)   // 2048
#define CHUNK_ELEMS (HW_/CHUNKS_PER_FRAME) // 16384
#define THREADS 256

#define BOUND_  100.0f
#define ALPHA_  0.1f
#define SMOOTH_ 1e-5f

typedef float f32x4 __attribute__((ext_vector_type(4)));

__device__ __forceinline__ float wave_reduce(float v) {
    #pragma unroll
    for (int off = 32; off >= 1; off >>= 1)
        v += __shfl_down(v, off, 64);
    return v;
}

// Pass 1: streaming partials, one contiguous 16K-element chunk per block.
// x is loaded normally (134 MB -> fully LLC-resident across replays);
// target is loaded non-temporally (nt: no LLC allocate) so it streams from
// HBM without evicting x or paying fill bandwidth.
// Partials in ws: [5][NBLOCKS] = {bce, pt, p, t, x}.
__global__ void __launch_bounds__(THREADS)
partials_kernel(const float* __restrict__ x, const float* __restrict__ tg,
                float* __restrict__ ws) {
    const int bid = blockIdx.x;
    const int tid = threadIdx.x;
    const size_t base = (size_t)bid * CHUNK_ELEMS;
    const f32x4* __restrict__ x4 = (const f32x4*)(x + base);
    const f32x4* __restrict__ t4 = (const f32x4*)(tg + base);

    float s_bce = 0.f, s_pt = 0.f, s_p = 0.f, s_t = 0.f, s_x = 0.f;

    const int n4 = CHUNK_ELEMS / 4;  // 4096 float4 per block, 16 iters/thread
    for (int i = tid; i < n4; i += THREADS) {
        f32x4 xv = x4[i];
        f32x4 tv = __builtin_nontemporal_load(&t4[i]);
        #pragma unroll
        for (int j = 0; j < 4; ++j) {
            float xx = xv[j], tt = tv[j];
            float ax = fabsf(xx);
            float e  = __expf(-ax);                    // shared by bce + sigmoid
            // bce: max(x,0) - x*t + log1p(exp(-|x|)); e in (0,1] so log is safe
            s_bce += fmaxf(xx, 0.f) - xx * tt + __logf(1.f + e);
            float inv = __fdividef(1.f, 1.f + e);
            float sig = (xx >= 0.f) ? inv : e * inv;   // sigmoid via same e
            s_pt += sig * tt;
            s_p  += sig;
            s_t  += tt;
            s_x  += xx;
        }
    }

    // block reduce (4 waves)
    __shared__ float red[4][5];
    float v[5] = {s_bce, s_pt, s_p, s_t, s_x};
    const int lane = tid & 63, wv = tid >> 6;
    #pragma unroll
    for (int q = 0; q < 5; ++q) {
        float r = wave_reduce(v[q]);
        if (lane == 0) red[wv][q] = r;
    }
    __syncthreads();
    if (tid == 0) {
        #pragma unroll
        for (int q = 0; q < 5; ++q)
            ws[q * NBLOCKS + bid] = red[0][q] + red[1][q] + red[2][q] + red[3][q];
    }
}

// Pass 2: single 256-thread block, fixed-order deterministic reductions.
__global__ void __launch_bounds__(256)
finalize_kernel(const float* __restrict__ ws, float* __restrict__ out) {
    __shared__ float frame_s[B_ * T_];   // 128 per-frame x sums
    __shared__ float batch_q[3][B_];     // pt, p, t per batch
    __shared__ float sred[4];
    __shared__ float ssl_sh;

    const int tid = threadIdx.x;
    const int lane = tid & 63, wv = tid >> 6;

    // phase 1: frame sums from x-partials (threads 0..127)
    if (tid < B_ * T_) {
        const float* wx = ws + 4 * NBLOCKS;
        float s = 0.f;
        #pragma unroll
        for (int j = 0; j < CHUNKS_PER_FRAME; ++j)
            s += wx[tid * CHUNKS_PER_FRAME + j];
        frame_s[tid] = s;
    }
    __syncthreads();

    // phase 2a: per-batch pt/p/t sums — 24 segments x 256 values, 8 threads each
    if (tid < 192) {
        int seg = tid >> 3;          // 0..23
        int q = seg >> 3;            // 0..2  -> ws segments 1..3
        int b = seg & 7;             // 0..7
        const float* wq = ws + (q + 1) * NBLOCKS + b * (NBLOCKS / B_);
        float s = 0.f;
        #pragma unroll
        for (int k = 0; k < 32; ++k)
            s += wq[(tid & 7) * 32 + k];
        s += __shfl_down(s, 4, 64);   // groups of 8 are wave-aligned
        s += __shfl_down(s, 2, 64);
        s += __shfl_down(s, 1, 64);
        if ((tid & 7) == 0) batch_q[q][b] = s;
    }
    // phase 2b: ssl over 120 frame diffs (threads 192..255 = wave 3, 2 diffs each)
    if (tid >= 192) {
        int k = tid - 192;
        float sslp = 0.f;
        #pragma unroll
        for (int u = 0; u < 2; ++u) {
            int kk = k + 64 * u;
            if (kk < B_ * (T_ - 1)) {
                int b = kk / (T_ - 1), j = kk % (T_ - 1);
                int f = b * T_ + j;
                float d = fabsf(frame_s[f + 1] - frame_s[f]);
                float r = fmaxf(d - BOUND_, 0.f);
                sslp += r * r;
            }
        }
        float r = wave_reduce(sslp);
        if (lane == 0) ssl_sh = r;
    }
    __syncthreads();

    // phase 3: global bce sum — 2048 partials, 8 per thread
    {
        float s = 0.f;
        #pragma unroll
        for (int k = 0; k < 8; ++k)
            s += ws[tid * 8 + k];
        float r = wave_reduce(s);
        if (lane == 0) sred[wv] = r;
    }
    __syncthreads();

    if (tid == 0) {
        float bce = (sred[0] + sred[1] + sred[2] + sred[3]) / (float)N_;
        float dice_sum = 0.f;
        #pragma unroll
        for (int b = 0; b < B_; ++b) {
            float inter = batch_q[0][b];
            dice_sum += (2.f * inter + SMOOTH_) /
                        (batch_q[1][b] + batch_q[2][b] + SMOOTH_);
        }
        float dice = 1.f - dice_sum / (float)B_;
        out[0] = 0.5f * bce + dice + ALPHA_ * ssl_sh;
    }
}

extern "C" void kernel_launch(void* const* d_in, const int* in_sizes, int n_in,
                              void* d_out, int out_size, void* d_ws, size_t ws_size,
                              hipStream_t stream) {
    const float* x  = (const float*)d_in[0];
    const float* tg = (const float*)d_in[1];
    float* ws = (float*)d_ws;          // 5*2048*4 = 40 KB partials
    float* out = (float*)d_out;

    partials_kernel<<<NBLOCKS, THREADS, 0, stream>>>(x, tg, ws);
    finalize_kernel<<<1, 256, 0, stream>>>(ws, out);
}